// Round 17
// baseline (120.411 us; speedup 1.0000x reference)
//
#include <hip/hip_runtime.h>

// out[n, mu, mup] = sum_{(m1,m2)∈T(mu)} sum_{(m1p,m2p)∈T(mup)}
//     c_p*c_q * X1[n,m1,m1p] * X2[n,m2,m2p],   T(mu)={m1+m2==mu+4}
// Rank-1 weights: sp*w0[q] = c_p*c_q, w0[q]=mult[q], sp=mult[p]/mult[0].
//
// R17: mu moves from WAVES into LANES. Since R3, 9 mu-waves re-read the same
// LDS rows (9x instruction amplification) and need barrier phases; R10-R16
// proved the structure insensitive to instrs/occupancy/staging/overlap (~27us
// phase-serialized). Here: block = 2 independent waves, wave owns 7 n,
// lane = n_local*9 + mu (lane 63 idle):
//  - x1 row reads: 9 lanes/n-group hit the SAME address -> LDS broadcast
//    (one issue) -> the 9x reuse becomes free. ~6x less LDS pipe.
//  - wave stages its OWN data -> same-wave in-order LDS -> ZERO barriers,
//    no chip-wide phase lock; blocks retire independently.
//  - branchless: invalid (mu,m1) get scale 0 (clamped reads * 0) -> no
//    divergence; all lanes run 9 uniform unrolled m1-iterations.
//  - LDS 9.1 KB/block -> ~14 blocks/CU = 28 waves.
// HARD RULES (R6/R8/R11): w0[61] inline, const-indexed only, never
// passed/addressed; spv[9] const-indexed (unrolled) only.

namespace {

struct QTab {
  int m1p[61];
  int m2p[61];
  int mup[61];
  constexpr QTab() : m1p{}, m2p{}, mup{} {
    int idx = 0;
    for (int mu = 0; mu < 9; ++mu)
      for (int a = 0; a < 9; ++a) {
        int b = mu + 4 - a;
        if (b >= 0 && b < 9) {
          m1p[idx] = a; m2p[idx] = b; mup[idx] = mu; ++idx;
        }
      }
  }
};
constexpr QTab QT{};

}  // namespace

__device__ __forceinline__ float uniform_f32(float v) {
  return __int_as_float(__builtin_amdgcn_readfirstlane(__float_as_int(v)));
}

#define NPW 7              // n per wave
#define NPB 14             // n per block (2 waves)
#define WDW (NPW * 81)     // 567 dwords per array per wave
#define NT 128             // 2 waves

__global__ __launch_bounds__(NT)
void wigner_combine_kernel(const float* __restrict__ X1,
                           const float* __restrict__ X2,
                           const float* __restrict__ mult,
                           float* __restrict__ out, int N) {
  __shared__ float x1s[2 * WDW];  // 4536 B
  __shared__ float x2s[2 * WDW];  // 4536 B

  const int t = threadIdx.x;
  const int wv = t >> 6;      // wave 0/1
  const int lane = t & 63;
  const int woff = wv * WDW;

  // ---- weight row 0 -> 61 SGPRs (inline, constant indices ONLY) ----
  float w0[61];
#pragma unroll
  for (int q = 0; q < 61; ++q) w0[q] = uniform_f32(mult[q]);
  const float inv00 = 1.0f / w0[0];

  // ---- stage this wave's own 567-dword slice of each array ----
  const long wbase = ((long)blockIdx.x * NPB + wv * NPW) * 81;
  const long total = (long)N * 81;
#pragma unroll
  for (int r = 0; r < 9; ++r) {
    const int idx = lane + r * 64;
    if (idx < WDW) {
      const long g = wbase + idx;
      float v1 = 0.0f, v2 = 0.0f;
      if (g < total) { v1 = X1[g]; v2 = X2[g]; }
      x1s[woff + idx] = v1;
      x2s[woff + idx] = v2;
    }
  }
  // NO __syncthreads: consumer is the same wave; LDS ops are in-order.

  // ---- lane roles: lane = nloc*9 + mu ----
  const int nloc = (lane < 63) ? (lane / 9) : 6;  // lane 63: clamped, inactive
  const int mu = lane - nloc * 9;                 // 0..8 (lane 63 -> 9)
  const bool alive = (lane < 63);
  const long nglob = (long)blockIdx.x * NPB + wv * NPW + nloc;
  const bool act = alive && (nglob < N);

  // pair-index prefix for this mu (closed form; mu=9 gives 61 -> safe reads)
  const int pref = (mu <= 4) ? (mu * (mu + 9)) / 2
                             : 26 + 9 * (mu - 4) - ((mu - 4) * (mu - 5)) / 2;
  const int m1lo = (mu - 4 > 0) ? mu - 4 : 0;

  // per-lane scale factors; 0 for invalid (mu,m1) -> branchless compute.
  // pidx stays in [0,64] for all lanes incl. clamped ones -> safe loads.
  float spv[9];
#pragma unroll
  for (int m1 = 0; m1 < 9; ++m1) {
    const int m2 = mu + 4 - m1;
    const bool v = alive && (m2 >= 0) && (m2 <= 8);
    const int pidx = pref + (m1 - m1lo);
    spv[m1] = v ? (mult[pidx] * inv00) : 0.0f;
  }

  const int nbase = woff + nloc * 81;

  float acc[9];
#pragma unroll
  for (int j = 0; j < 9; ++j) acc[j] = 0.0f;

#pragma unroll
  for (int m1 = 0; m1 < 9; ++m1) {
    const int m2 = mu + 4 - m1;
    const int m2c = (m2 < 0) ? 0 : ((m2 > 8) ? 8 : m2);  // clamped; *0 if invalid

    float x1w[9], x2r[9];
#pragma unroll
    for (int j = 0; j < 9; ++j)
      x1w[j] = x1s[nbase + m1 * 9 + j] * spv[m1];  // same addr for 9 lanes -> broadcast
    const int x2b = nbase + m2c * 9;
#pragma unroll
    for (int j = 0; j < 9; ++j) x2r[j] = x2s[x2b + j];

#pragma unroll
    for (int q = 0; q < 61; ++q) {
      // weight = spv[m1] * w0[q] = c_p * c_q; w0 const-indexed (SGPRs)
      acc[QT.mup[q]] = fmaf(w0[q], x1w[QT.m1p[q]] * x2r[QT.m2p[q]],
                            acc[QT.mup[q]]);
    }
  }

  // ---- stores: 9-lane groups cover 324 contiguous bytes per n ----
  if (act) {
    float* __restrict__ op = out + nglob * 81 + mu * 9;
#pragma unroll
    for (int j = 0; j < 9; ++j) op[j] = acc[j];
  }
}

extern "C" void kernel_launch(void* const* d_in, const int* in_sizes, int n_in,
                              void* d_out, int out_size, void* d_ws, size_t ws_size,
                              hipStream_t stream) {
  const float* X1 = (const float*)d_in[0];
  const float* X2 = (const float*)d_in[1];
  const float* mult = (const float*)d_in[6];
  float* out = (float*)d_out;

  const int N = in_sizes[0] / 81;
  const int blocks = (N + NPB - 1) / NPB;
  wigner_combine_kernel<<<blocks, NT, 0, stream>>>(X1, X2, mult, out, N);
}

// Round 18
// 103.475 us; speedup vs baseline: 1.1637x; 1.1637x over previous
//
#include <hip/hip_runtime.h>

// out[n, mu, mup] = sum_{(m1,m2)∈T(mu)} sum_{(m1p,m2p)∈T(mup)}
//     c_p*c_q * X1[n,m1,m1p] * X2[n,m2,m2p],   T(mu)={m1+m2==mu+4}
// Rank-1 weights: sp*w0[q] = c_p*c_q, w0[q]=mult[q], sp=csh[p]=mult[p]/mult[0].
//
// R18 = R15 (best measured, dur_us 103.1) + per-pair tmp accumulator: inner
// 61 FMAs use raw w0 weights into tmp[9], sp applied once at pair end
// (acc[j] += sp*tmp[j]) -> inner chain doesn't wait on the LDS-sourced sp.
// Session ledger: R10/R15 ~23us kernel; six structural experiments
// (R11-R17) produced 0 wins / 3 regressions / 3 neutrals -> the kernel is a
// single-generation launch (~28 waves/CU total work < residency) paying
// unoverlappable ramp (launch + cold fetch ~5us + compute ~10us + store
// drain ~3us); no partitioning creates a 2nd generation to hide phases.
// HARD RULES (R6/R8/R11): w0[61] inline, const-indexed only, never
// passed/addressed. No runtime-indexed register arrays.

namespace {

struct QTab {
  int m1p[61];
  int m2p[61];
  int mup[61];
  constexpr QTab() : m1p{}, m2p{}, mup{} {
    int idx = 0;
    for (int mu = 0; mu < 9; ++mu)
      for (int a = 0; a < 9; ++a) {
        int b = mu + 4 - a;
        if (b >= 0 && b < 9) {
          m1p[idx] = a; m2p[idx] = b; mup[idx] = mu; ++idx;
        }
      }
  }
};
constexpr QTab QT{};

}  // namespace

// pairs per mu: [5,6,7,8,9,8,7,6,5]; prefix = first pair index of each mu
__constant__ __device__ int kPrefix[9] = {0, 5, 11, 18, 26, 35, 43, 50, 56};

__device__ __forceinline__ float uniform_f32(float v) {
  return __int_as_float(__builtin_amdgcn_readfirstlane(__float_as_int(v)));
}

typedef unsigned int u32;

// Async global->LDS DMA. LDS dest = uniform base + lane*SZ (16 or 4 bytes).
__device__ __forceinline__ void glds16(const float* g, float* lds) {
  __builtin_amdgcn_global_load_lds(
      (const __attribute__((address_space(1))) u32*)g,
      (__attribute__((address_space(3))) u32*)(u32)(uintptr_t)lds, 16, 0, 0);
}
__device__ __forceinline__ void glds4(const float* g, float* lds) {
  __builtin_amdgcn_global_load_lds(
      (const __attribute__((address_space(1))) u32*)g,
      (__attribute__((address_space(3))) u32*)(u32)(uintptr_t)lds, 4, 0, 0);
}

#define NB 64            // n per block
#define NT 576           // threads = 9 waves (wave = mu, lane = n-local)
#define AD (NB * 81)     // 5184 dwords per array per block
#define CH 256           // dwords per x16 wave-chunk (64 lanes * 4 dw)
#define NCH 20           // full x16 chunks per array (20*256 = 5120)
#define TAILB 5120       // tail base (64 dwords, staged at width 4)

__global__ __launch_bounds__(NT)
void wigner_combine_kernel(const float* __restrict__ X1,
                           const float* __restrict__ X2,
                           const float* __restrict__ mult,
                           float* __restrict__ out, int N) {
  __shared__ __align__(16) float x1s[AD];  // 20736 B, linear [n][81]
  __shared__ __align__(16) float x2s[AD];  // 20736 B
  __shared__ float csh[61];                // per-pair scales c_p/c_p0

  const int t = threadIdx.x;
  const int w = t >> 6;      // wave id 0..8
  const int lane = t & 63;
  const long gbase = (long)blockIdx.x * AD;  // dword base of this block
  const long totaldw = (long)N * 81;

  // ---- weight row 0 -> 61 SGPRs (inline, constant indices ONLY) ----
  float w0[61];
#pragma unroll
  for (int q = 0; q < 61; ++q) w0[q] = uniform_f32(mult[q]);

  if (t < 61) csh[t] = mult[t] * (1.0f / mult[0]);

  // ---- stage: async linear DMA, both arrays. 40 x16 chunks + 2 x4 tails
  // distributed over 9 waves. Per-lane guard only binds in the last block.
#pragma unroll
  for (int k = 0; k < 5; ++k) {
    const int i = w + 9 * k;  // wave-uniform chunk id
    if (i < 2 * NCH) {
      const int cbase = (i < NCH ? i : i - NCH) * CH;
      const float* gsrc = (i < NCH ? X1 : X2) + gbase + cbase + lane * 4;
      float* ldst = (i < NCH ? x1s : x2s) + cbase;
      if (gbase + cbase + lane * 4 < totaldw) glds16(gsrc, ldst);
    }
  }
  if (w == 0) {
    if (gbase + TAILB + lane < totaldw)
      glds4(X1 + gbase + TAILB + lane, x1s + TAILB);
  } else if (w == 1) {
    if (gbase + TAILB + lane < totaldw)
      glds4(X2 + gbase + TAILB + lane, x2s + TAILB);
  }
  __syncthreads();  // vmcnt(0) drains the DMA

  // ---- compute: wave = mu, lane = local n ----
  const int mu = __builtin_amdgcn_readfirstlane(w);  // wave-uniform
  const int m1lo = (mu - 4 > 0) ? mu - 4 : 0;
  const int pbase = kPrefix[mu];

  const float* __restrict__ lx1 = x1s + lane * 81;  // stride 81 odd -> 2-way free
  const float* __restrict__ lx2 = x2s + lane * 81;

  float acc[9];
#pragma unroll
  for (int j = 0; j < 9; ++j) acc[j] = 0.0f;

#pragma unroll
  for (int m1 = 0; m1 < 9; ++m1) {
    const int m2 = mu + 4 - m1;      // wave-uniform scalar
    if (m2 < 0 || m2 > 8) continue;  // uniform guard (scalar branch)
    const int p = pbase + (m1 - m1lo);
    const float sp = csh[p];         // uniform ds_read broadcast, in-order

    float x1r[9], x2r[9];
#pragma unroll
    for (int j = 0; j < 9; ++j) x1r[j] = lx1[m1 * 9 + j];
#pragma unroll
    for (int j = 0; j < 9; ++j) x2r[j] = lx2[m2 * 9 + j];

    // inner FMAs independent of sp (LDS-sourced); sp applied once per pair
    float tmp[9];
#pragma unroll
    for (int j = 0; j < 9; ++j) tmp[j] = 0.0f;
#pragma unroll
    for (int q = 0; q < 61; ++q)
      tmp[QT.mup[q]] = fmaf(w0[q], x1r[QT.m1p[q]] * x2r[QT.m2p[q]],
                            tmp[QT.mup[q]]);
#pragma unroll
    for (int j = 0; j < 9; ++j) acc[j] = fmaf(sp, tmp[j], acc[j]);
  }

  // ---- direct stores: out[n, mu, 0..8] (same-block waves cover all 81
  // components of each n -> L2 merges to full lines) ----
  const long n = (long)blockIdx.x * NB + lane;
  if (n < N) {
    float* __restrict__ op = out + n * 81 + mu * 9;
#pragma unroll
    for (int j = 0; j < 9; ++j) op[j] = acc[j];
  }
}

extern "C" void kernel_launch(void* const* d_in, const int* in_sizes, int n_in,
                              void* d_out, int out_size, void* d_ws, size_t ws_size,
                              hipStream_t stream) {
  const float* X1 = (const float*)d_in[0];
  const float* X2 = (const float*)d_in[1];
  const float* mult = (const float*)d_in[6];
  float* out = (float*)d_out;

  const int N = in_sizes[0] / 81;
  const int blocks = (N + NB - 1) / NB;
  wigner_combine_kernel<<<blocks, NT, 0, stream>>>(X1, X2, mult, out, N);
}